// Round 12
// baseline (39271.219 us; speedup 1.0000x reference)
//
#include <hip/hip_runtime.h>
#include <hip/hip_bf16.h>
#include <hip/hip_fp16.h>

// ---------------------------------------------------------------------------
// LuxrNet: conv->conv->FFN (parallel branch) + 2-layer GRU over a 32768-step
// flattened scan (serial branch) + joiner + output head.
// Round 8..12: two scan kernels; each scan is 512-thread QUAD-split:
// thread (o = t>>2, c = t&3) holds 48 packed-f16 weights (fits ARCHITECTED
// VGPRs -- R4/R6/R7 all paid a v_accvgpr_read tax on AGPR-parked weights),
// 48 fdot2/step, 4-lane shfl_xor reduce, 2 waves/SIMD for latency hiding.
// ---------------------------------------------------------------------------

typedef _Float16 h2_t __attribute__((ext_vector_type(2)));

#if defined(__has_builtin)
#if __has_builtin(__builtin_amdgcn_fdot2)
#define HAVE_FDOT2 1
#endif
#endif

__device__ __forceinline__ h2_t f2h2bits(float x) {
  union { float f; h2_t h; } u; u.f = x; return u.h;
}

__device__ __forceinline__ float fdot2(h2_t a, h2_t b, float c) {
#ifdef HAVE_FDOT2
  return __builtin_amdgcn_fdot2(a, b, c, false);
#else
  return c + (float)a.x * (float)b.x + (float)a.y * (float)b.y;
#endif
}

__device__ __forceinline__ float sigmoidf_(float x) {
  return 1.f / (1.f + __expf(-x));
}
__device__ __forceinline__ float tanhf_(float x) {
  return 2.f / (1.f + __expf(-2.f * x)) - 1.f;
}

// ---------------------------------------------------------------------------
// conv1: in (512,10,30,30), w (64,10,8,8), stride 2 -> out (512,64,12,12), relu
// ---------------------------------------------------------------------------
__global__ __launch_bounds__(256) void conv1_k(
    const float* __restrict__ in, const float* __restrict__ w,
    const float* __restrict__ bias, float* __restrict__ out) {
  int idx = blockIdx.x * 256 + threadIdx.x;     // 512*64*144 total, exact
  int pos = idx % 144;
  int co  = (idx / 144) & 63;
  int b   = idx / (144 * 64);
  int oh = pos / 12, ow = pos % 12;
  const float* ip = in + (size_t)b * 9000 + (oh * 2) * 30 + ow * 2;
  const float* wp = w + co * 640;
  float acc = bias[co];
  for (int ci = 0; ci < 10; ci++) {
#pragma unroll
    for (int kh = 0; kh < 8; kh++) {
      const float* r  = ip + ci * 900 + kh * 30;
      const float* wr = wp + ci * 64 + kh * 8;
#pragma unroll
      for (int kw = 0; kw < 8; kw++) acc += r[kw] * wr[kw];
    }
  }
  out[idx] = fmaxf(acc, 0.f);
}

// ---------------------------------------------------------------------------
// conv2: in (512,64,12,12), w (128,64,4,4), stride 2 -> out (512,128,5,5), relu
// ---------------------------------------------------------------------------
__global__ __launch_bounds__(256) void conv2_k(
    const float* __restrict__ in, const float* __restrict__ w,
    const float* __restrict__ bias, float* __restrict__ out) {
  int idx = blockIdx.x * 256 + threadIdx.x;     // 512*128*25 total, exact
  int pos = idx % 25;
  int co  = (idx / 25) & 127;
  int b   = idx / 3200;
  int oh = pos / 5, ow = pos % 5;
  const float* ip = in + (size_t)b * 9216 + (oh * 2) * 12 + ow * 2;
  const float* wp = w + co * 1024;
  float acc = bias[co];
  for (int ci = 0; ci < 64; ci++) {
#pragma unroll
    for (int kh = 0; kh < 4; kh++) {
      const float* r  = ip + ci * 144 + kh * 12;
      const float* wr = wp + ci * 16 + kh * 4;
#pragma unroll
      for (int kw = 0; kw < 4; kw++) acc += r[kw] * wr[kw];
    }
  }
  out[idx] = fmaxf(acc, 0.f);
}

// ---------------------------------------------------------------------------
// Generic fp32 GEMM: C[m*ldc+n] = bias[n] + sum_k X[m*K+k] * W[n*K+k]
// Requires M%64==0, N%64==0, K%16==0. 64x64 tile, 256 threads, 4x4 micro.
// ---------------------------------------------------------------------------
__global__ __launch_bounds__(256) void gemm_xwt(
    const float* __restrict__ X, const float* __restrict__ W,
    const float* __restrict__ bias, float* __restrict__ C,
    int M, int N, int K, int ldc, int relu) {
  __shared__ float Xs[16][68];
  __shared__ float Ws[16][68];
  int tid = threadIdx.x;
  int m0 = blockIdx.y * 64, n0 = blockIdx.x * 64;
  int lr = tid >> 2;            // 0..63
  int lc = (tid & 3) << 2;      // 0,4,8,12
  int tm = tid >> 4, tn = tid & 15;
  float acc[4][4] = {};
  for (int k0 = 0; k0 < K; k0 += 16) {
    const float4 xv = *(const float4*)(X + (size_t)(m0 + lr) * K + k0 + lc);
    const float4 wv = *(const float4*)(W + (size_t)(n0 + lr) * K + k0 + lc);
    Xs[lc + 0][lr] = xv.x; Xs[lc + 1][lr] = xv.y;
    Xs[lc + 2][lr] = xv.z; Xs[lc + 3][lr] = xv.w;
    Ws[lc + 0][lr] = wv.x; Ws[lc + 1][lr] = wv.y;
    Ws[lc + 2][lr] = wv.z; Ws[lc + 3][lr] = wv.w;
    __syncthreads();
#pragma unroll
    for (int kk = 0; kk < 16; kk++) {
      float a[4], bb[4];
#pragma unroll
      for (int i = 0; i < 4; i++) a[i] = Xs[kk][tm * 4 + i];
#pragma unroll
      for (int j = 0; j < 4; j++) bb[j] = Ws[kk][tn * 4 + j];
#pragma unroll
      for (int i = 0; i < 4; i++)
#pragma unroll
        for (int j = 0; j < 4; j++) acc[i][j] += a[i] * bb[j];
    }
    __syncthreads();
  }
#pragma unroll
  for (int i = 0; i < 4; i++) {
    int m = m0 + tm * 4 + i;
#pragma unroll
    for (int j = 0; j < 4; j++) {
      int n = n0 + tn * 4 + j;
      float v = acc[i][j] + bias[n];
      if (relu) v = fmaxf(v, 0.f);
      C[(size_t)m * ldc + n] = v;
    }
  }
}

// ---------------------------------------------------------------------------
// gi0 = seq @ wih0^T + bih0 where seq[s] = uf[s&511, s>>9, :]  (K=8).
// ---------------------------------------------------------------------------
__global__ __launch_bounds__(384) void gi0_k(
    const float* __restrict__ uf,   // (512,64,8)
    const float* __restrict__ wih,  // (384,8)
    const float* __restrict__ bih,  // (384)
    float* __restrict__ gi) {       // (32768,384)
  int n = threadIdx.x;
  int s0 = blockIdx.x * 32;
  __shared__ float xs[32][8];
  if (n < 256) {
    int ss = s0 + (n >> 3);
    int k = n & 7;
    xs[n >> 3][k] = uf[(size_t)(ss & 511) * 512 + (ss >> 9) * 8 + k];
  }
  float w[8];
#pragma unroll
  for (int k = 0; k < 8; k++) w[k] = wih[n * 8 + k];
  float b = bih[n];
  __syncthreads();
#pragma unroll 4
  for (int i = 0; i < 32; i++) {
    float a = b;
#pragma unroll
    for (int k = 0; k < 8; k++) a += w[k] * xs[i][k];
    gi[(size_t)(s0 + i) * 384 + n] = a;
  }
}

// ---------------------------------------------------------------------------
// GRU scan, round-8 structure: 512 threads, QUAD-split.
// Thread (o = t>>2, c = t&3) owns output o, K-quarter [c*32, c*32+32):
//   - 48 packed-f16 weights (16 h2 per gate) -> 48 VGPRs, fits architected
//     file at 2 waves/SIMD (cap 256): no AGPR shuffle tax.
//   - per step: 4x ds_read_b128 (only 4 distinct addrs/wave -> broadcast;
//     c0/c2 and c1/c3 2-way alias = free), 48 fdot2,
//     reduce shfl_xor(1)+shfl_xor(2), gates redundant in all 4 lanes.
//   - ONE barrier per step (lgkmcnt-only), depth-2 register gi prefetch.
// LAYER0: writes h1[s] (c==0 lanes); LAYER1: writes jx tail.
// ---------------------------------------------------------------------------
#define QSTEP(HIN, HOUT, G0, G1, G2, SIDX)                                    \
  {                                                                           \
    const float4* hp4 = (const float4*)(&HIN[c * 32]);                        \
    float ar = b0, az = b1, an = b2;                                          \
    _Pragma("unroll")                                                         \
    for (int q = 0; q < 4; q++) {                                             \
      float4 blk = hp4[q];                                                    \
      h2_t x0 = f2h2bits(blk.x), x1 = f2h2bits(blk.y);                        \
      h2_t x2 = f2h2bits(blk.z), x3 = f2h2bits(blk.w);                        \
      ar = fdot2(w0[4*q+0], x0, ar); az = fdot2(w1[4*q+0], x0, az);           \
      an = fdot2(w2[4*q+0], x0, an);                                          \
      ar = fdot2(w0[4*q+1], x1, ar); az = fdot2(w1[4*q+1], x1, az);           \
      an = fdot2(w2[4*q+1], x1, an);                                          \
      ar = fdot2(w0[4*q+2], x2, ar); az = fdot2(w1[4*q+2], x2, az);           \
      an = fdot2(w2[4*q+2], x2, an);                                          \
      ar = fdot2(w0[4*q+3], x3, ar); az = fdot2(w1[4*q+3], x3, az);           \
      an = fdot2(w2[4*q+3], x3, an);                                          \
    }                                                                         \
    ar += __shfl_xor(ar, 1); az += __shfl_xor(az, 1); an += __shfl_xor(an, 1);\
    ar += __shfl_xor(ar, 2); az += __shfl_xor(az, 2); an += __shfl_xor(an, 2);\
    float r = sigmoidf_((G0) + ar);                                           \
    float z = sigmoidf_((G1) + az);                                           \
    float n = tanhf_((G2) + r * an);                                          \
    float hn = (1.f - z) * n + z * hreg;                                      \
    hreg = hn;                                                                \
    if (c == 0) {                                                             \
      HOUT[o] = (_Float16)hn;                                                 \
      if (LAYER == 0) {                                                       \
        h_out[(size_t)(SIDX) * 128 + o] = hn;                                 \
      } else if ((SIDX) >= S - 512) {                                         \
        jx[(size_t)((SIDX) - (S - 512)) * 640 + 512 + o] = hn;                \
      }                                                                       \
    }                                                                         \
  }

#define GRU_RELOAD(G0, G1, G2)                                                \
  { G0 = gp[0]; G1 = gp[128]; G2 = gp[256]; gp += 768; }

#define GRU_BARRIER()                                                         \
  __builtin_amdgcn_sched_barrier(0);                                          \
  asm volatile("s_waitcnt lgkmcnt(0)" ::: "memory");                          \
  __builtin_amdgcn_s_barrier();                                               \
  __builtin_amdgcn_sched_barrier(0);

template <int LAYER>
__global__ __launch_bounds__(512, 2) void gru_scan4(
    const float* __restrict__ gi,    // (S,384), includes bih
    const float* __restrict__ whh,   // (384,128)
    const float* __restrict__ bhh,   // (384)
    float* __restrict__ h_out,       // LAYER0: h1 (S,128)
    float* __restrict__ jx) {        // LAYER1: (512,640), cols 512..639
  const int S = 32768;
  const int t = threadIdx.x;
  const int o = t >> 2;      // output index 0..127
  const int c = t & 3;       // K-quarter 0..3

  alignas(16) __shared__ _Float16 hbuf0[128];
  alignas(16) __shared__ _Float16 hbuf1[128];

  // 48 packed-f16 weights: 16 h2 per gate, this thread's K-quarter.
  h2_t w0[16], w1[16], w2[16];
  {
    const float2* pr = (const float2*)(whh + (size_t)(o)       * 128 + c * 32);
    const float2* pz = (const float2*)(whh + (size_t)(128 + o) * 128 + c * 32);
    const float2* pn = (const float2*)(whh + (size_t)(256 + o) * 128 + c * 32);
#pragma unroll
    for (int k = 0; k < 16; k++) {
      float2 a = pr[k], b = pz[k], d = pn[k];
      h2_t va; va.x = (_Float16)a.x; va.y = (_Float16)a.y; w0[k] = va;
      h2_t vb; vb.x = (_Float16)b.x; vb.y = (_Float16)b.y; w1[k] = vb;
      h2_t vc; vc.x = (_Float16)d.x; vc.y = (_Float16)d.y; w2[k] = vc;
    }
  }
  // bhh counted once across the 4-lane reduce (c==0 only)
  float b0 = 0.f, b1 = 0.f, b2 = 0.f;
  if (c == 0) { b0 = bhh[o]; b1 = bhh[128 + o]; b2 = bhh[256 + o]; }

  float hreg = 0.f;
  if (t < 128) hbuf0[t] = (_Float16)0.f;

  // depth-2 register prefetch of gi rows (all 4 c-lanes load the same
  // 3 addresses -> wave-coalesced broadcast, L1/L2-served)
  const float* gp = gi + o;
  float gA0, gA1, gA2, gB0, gB1, gB2;
  { gA0 = gp[0]; gA1 = gp[128]; gA2 = gp[256]; gp += 384; }
  { gB0 = gp[0]; gB1 = gp[128]; gB2 = gp[256]; gp += 384; }
  __syncthreads();

  // NOTE: final reloads read gi rows S..S+1 -> land in the h1 region of
  // d_ws (in-bounds, values never consumed).
  for (int s = 0; s < S; s += 2) {
    QSTEP(hbuf0, hbuf1, gA0, gA1, gA2, s);
    GRU_RELOAD(gA0, gA1, gA2);
    GRU_BARRIER();
    QSTEP(hbuf1, hbuf0, gB0, gB1, gB2, s + 1);
    { gB0 = gp[-384]; gB1 = gp[-256]; gB2 = gp[-128]; }
    GRU_BARRIER();
  }
}

// ---------------------------------------------------------------------------
// out head: out[b,:] = hidden[b,:] @ out_w.T + out_b (relu pre-applied)
// ---------------------------------------------------------------------------
__global__ __launch_bounds__(64) void out_k(
    const float* __restrict__ hidden, const float* __restrict__ ow,
    const float* __restrict__ ob, float* __restrict__ out) {
  __shared__ float hrow[512];
  int b = blockIdx.x, t = threadIdx.x;
  float4* h4 = (float4*)hrow;
  const float4* src = (const float4*)(hidden + (size_t)b * 512);
  h4[t] = src[t];
  h4[t + 64] = src[t + 64];
  __syncthreads();
  if (t < 12) {
    float acc = ob[t];
    const float* wr = ow + t * 512;
    for (int k = 0; k < 512; k++) acc += hrow[k] * wr[k];
    out[(size_t)b * 12 + t] = acc;
  }
}

// ---------------------------------------------------------------------------
extern "C" void kernel_launch(void* const* d_in, const int* in_sizes, int n_in,
                              void* d_out, int out_size, void* d_ws,
                              size_t ws_size, hipStream_t stream) {
  const float* gf    = (const float*)d_in[0];   // (512,10,30,30)
  const float* uf    = (const float*)d_in[1];   // (512,64,8)
  const float* c1w   = (const float*)d_in[2];
  const float* c1b   = (const float*)d_in[3];
  const float* c2w   = (const float*)d_in[4];
  const float* c2b   = (const float*)d_in[5];
  const float* ffw   = (const float*)d_in[6];
  const float* ffb   = (const float*)d_in[7];
  const float* wih0  = (const float*)d_in[8];
  const float* whh0  = (const float*)d_in[9];
  const float* bih0  = (const float*)d_in[10];
  const float* bhh0  = (const float*)d_in[11];
  const float* wih1  = (const float*)d_in[12];
  const float* whh1  = (const float*)d_in[13];
  const float* bih1  = (const float*)d_in[14];
  const float* bhh1  = (const float*)d_in[15];
  const float* jw    = (const float*)d_in[16];
  const float* jb    = (const float*)d_in[17];
  const float* ow    = (const float*)d_in[18];
  const float* ob    = (const float*)d_in[19];
  float* outp = (float*)d_out;                  // (512,12)

  // workspace layout (floats). gi buffer time-shares with conv scratch
  // (conv1o/conv2o dead before gi0 is written) and is reused for gi1.
  float* ws     = (float*)d_ws;
  float* gi     = ws;                 // 32768*384 = 12,582,912 f
  float* conv1o = ws;                 //  4,718,592 f (aliases gi, earlier)
  float* conv2o = ws + 4718592;       //  1,638,400 f (aliases gi, earlier)
  float* h1     = ws + 12582912;      //  4,194,304 f
  float* jx     = h1 + 4194304;       //  512*640 = 327,680 f
  float* hidden = jx + 327680;        //  512*512 = 262,144 f
  // total: 17,367,040 floats = ~66.3 MB

  conv1_k<<<18432, 256, 0, stream>>>(gf, c1w, c1b, conv1o);
  conv2_k<<<6400, 256, 0, stream>>>(conv1o, c2w, c2b, conv2o);
  // glob = conv2o(512,3200) @ ffw.T + ffb -> jx cols [0,512)
  gemm_xwt<<<dim3(8, 8), 256, 0, stream>>>(conv2o, ffw, ffb, jx,
                                           512, 512, 3200, 640, 0);
  // gi0 = seq @ wih0^T + bih0  (overwrites conv scratch, now dead)
  gi0_k<<<1024, 384, 0, stream>>>(uf, wih0, bih0, gi);
  // GRU layer 0
  gru_scan4<0><<<1, 512, 0, stream>>>(gi, whh0, bhh0, h1, nullptr);
  // gi1 = h1(32768,128) @ wih1.T + bih1  (overwrites gi0, now dead)
  gemm_xwt<<<dim3(6, 512), 256, 0, stream>>>(h1, wih1, bih1, gi,
                                             32768, 384, 128, 384, 0);
  // GRU layer 1, writes last 512 h's into jx cols [512,640)
  gru_scan4<1><<<1, 512, 0, stream>>>(gi, whh1, bhh1, nullptr, jx);
  // hidden = relu(jx(512,640) @ jw.T + jb)
  gemm_xwt<<<dim3(8, 8), 256, 0, stream>>>(jx, jw, jb, hidden,
                                           512, 512, 640, 512, 1);
  out_k<<<512, 64, 0, stream>>>(hidden, ow, ob, outp);
}